// Round 15
// baseline (22.433 us; speedup 1.0000x reference)
//
#include <hip/hip_runtime.h>
#include <math.h>

#define DIMQ 16
#define HID  128
#define SPB  32          // samples per block (8 waves; each wave owns ONE 16-h tile, all samples)
#define NTHREADS 512

typedef __attribute__((ext_vector_type(8))) _Float16 f16x8;  // MFMA A/B frag (4 VGPRs)
typedef __attribute__((ext_vector_type(4))) _Float16 f16x4;  // packed b64 store
typedef __attribute__((ext_vector_type(4))) float f32x4;     // MFMA acc
typedef __attribute__((ext_vector_type(2))) float v2f;       // packed f32 (v_pk_fma_f32)

// f16 strides (elements)
#define ASTR 280         // ABT[16][280]: [A^T | B^T], 560B row (16B-mult)
#define USTR 280         // usp[32][280]: u at h'=0..127, -sp at h'=128..255
#define SSTR 136         // sst[32][136]: s values

// LDS layout (bytes). Mscr overlays [0,40960) AFTER barrier #2 (all regions dead by then).
#define OFF_WFF  0       // f16 frag-major [8][4][16][8] = 8192
#define OFF_YFF  8192    // f16 frag-major [2][4][16][8] = 2048 -> 10240
#define OFF_ABT  10240   // f16[16][280] = 8960 -> 19200
#define OFF_USP  19200   // f16[32][280] = 17920 -> 37120
#define OFF_SST  37120   // f16[32][136] = 8704 -> 45824
#define OFF_MSCR 0       // f32 32*320 = 40960 (overlay)
#define LDS_BYTES 45824

// XOR-swizzle inside each sample's 320-f32 M-scratch (v7-validated).
__device__ __forceinline__ int mswz(int s, int off) {
    return s * 320 + (off ^ ((s & 7) << 2));
}
__device__ __forceinline__ f16x8 pack8(float4 a, float4 b) {
    f16x8 r;
    r[0]=(_Float16)a.x; r[1]=(_Float16)a.y; r[2]=(_Float16)a.z; r[3]=(_Float16)a.w;
    r[4]=(_Float16)b.x; r[5]=(_Float16)b.y; r[6]=(_Float16)b.z; r[7]=(_Float16)b.w;
    return r;
}

// block=512: __launch_bounds__(512,6) -> VGPR cap ~85 -> 6 waves/SIMD = 24 waves/CU
// = 3 resident 8-wave blocks (was ~2 at VGPR>85). Occupancy is the binding constraint.
__global__ __launch_bounds__(NTHREADS, 6)
void lag_accel_kernel(const float* __restrict__ y,    // [BATCH][32]
                      const float* __restrict__ W1,   // [128][32]
                      const float* __restrict__ b1,   // [128]
                      const float* __restrict__ w2,   // [128]
                      float* __restrict__ out)        // [BATCH][16]
{
    __shared__ __align__(16) char smem[LDS_BYTES];
    _Float16* Wff = (_Float16*)(smem + OFF_WFF);   // frag-major W1 rows
    _Float16* Yff = (_Float16*)(smem + OFF_YFF);   // frag-major y
    _Float16* ABT = (_Float16*)(smem + OFF_ABT);   // [16][280]: [j][h]=A[h][j], [j][128+h]=B[h][j]
    _Float16* usp = (_Float16*)(smem + OFF_USP);   // [32][280]: u / -sp
    _Float16* sst = (_Float16*)(smem + OFF_SST);   // [32][136]: s

    const int tid = threadIdx.x;
    const long long s0 = (long long)blockIdx.x * SPB;

    // ---- staging (all vectorized b128/b64 writes) ----
    {
        const int ht_ = tid >> 6, grp_ = (tid >> 4) & 3, j_ = tid & 15;
        const float4* src = (const float4*)(W1 + (ht_ * 16 + j_) * 32 + (grp_ << 3));
        *(f16x8*)&Wff[tid * 8] = pack8(src[0], src[1]);
    }
    if (tid < 256) {
        const int st_ = tid >> 7, grp_ = (tid >> 5) & 3, j_ = (tid >> 1) & 15, hf = tid & 1;
        float4 v = *(const float4*)(y + (s0 + st_ * 16 + j_) * 32 + (grp_ << 3) + (hf << 2));
        f16x4 p; p[0]=(_Float16)v.x; p[1]=(_Float16)v.y; p[2]=(_Float16)v.z; p[3]=(_Float16)v.w;
        *(f16x4*)&Yff[(((st_ * 4 + grp_) * 16 + j_) << 3) + (hf << 2)] = p;
    }
    {
        const int k = tid & 31, h0 = (tid >> 5) << 3;
        float v[8];
#pragma unroll
        for (int i = 0; i < 8; ++i) v[i] = W1[(h0 + i) * 32 + k];
        f16x8 p;
#pragma unroll
        for (int i = 0; i < 8; ++i) p[i] = (_Float16)v[i];
        const int j_ = (k < 16) ? k : (k - 16);
        const int off = (k < 16) ? h0 : (128 + h0);
        *(f16x8*)&ABT[j_ * ASTR + off] = p;
    }

    const int wave = tid >> 6;
    const int lane = tid & 63;
    const int grp  = lane >> 4;      // MFMA quadrant (k-slice / D row-block)
    const int j    = lane & 15;      // MFMA m/n index
    const int ht   = wave;           // this wave's h-tile (h = 16*ht .. 16*ht+15)

    __syncthreads();   // barrier 0: staging complete

    // b1/w2 loaded here (not before the barrier) to shorten cross-phase liveness.
    float4 b1v = *(const float4*)&b1[ht * 16 + (grp << 2)];
    float4 w2v = *(const float4*)&w2[ht * 16 + (grp << 2)];

    // ---- z/aqd GEMM: z = [A|B].y + b1 and aqd = [0|A].y (K=32), per h-tile ----
    f16x8 aW  = *(const f16x8*)&Wff[((ht * 4 + grp) * 16 + j) * 8];
    f16x8 aAl = *(const f16x8*)&Wff[((ht * 4 + (grp & 1)) * 16 + j) * 8];
    f16x8 aA;
#pragma unroll
    for (int e = 0; e < 8; ++e) aA[e] = (grp >= 2) ? aAl[e] : (_Float16)0.0f;

    f32x4 zacc[2], aacc[2];
    {
        f32x4 ci; ci[0] = b1v.x; ci[1] = b1v.y; ci[2] = b1v.z; ci[3] = b1v.w;
        f32x4 zf = {0.0f, 0.0f, 0.0f, 0.0f};
        f16x8 yf0 = *(const f16x8*)&Yff[((0 * 4 + grp) * 16 + j) * 8];
        f16x8 yf1 = *(const f16x8*)&Yff[((1 * 4 + grp) * 16 + j) * 8];
        zacc[0] = __builtin_amdgcn_mfma_f32_16x16x32_f16(aW, yf0, ci, 0, 0, 0);
        zacc[1] = __builtin_amdgcn_mfma_f32_16x16x32_f16(aW, yf1, ci, 0, 0, 0);
        aacc[0] = __builtin_amdgcn_mfma_f32_16x16x32_f16(aA, yf0, zf, 0, 0, 0);
        aacc[1] = __builtin_amdgcn_mfma_f32_16x16x32_f16(aA, yf1, zf, 0, 0, 0);
    }

    // ---- elementwise: t,u,s,sp per (h = 16ht+4grp+r, smp = 16st+j); stage f16 ----
    const int h4 = ht * 16 + (grp << 2);
#define EWST(st)                                                         \
    {                                                                    \
        _Float16 su[4], sn[4], sv[4];                                    \
        _Pragma("unroll")                                                \
        for (int r = 0; r < 4; ++r) {                                    \
            float z  = zacc[st][r], aq = aacc[st][r];                    \
            float w2c = (r == 0) ? w2v.x : (r == 1) ? w2v.y               \
                       : (r == 2) ? w2v.z : w2v.w;                       \
            float e  = __expf(2.0f * z);                                 \
            float rr = 2.0f * __builtin_amdgcn_rcpf(e + 1.0f);           \
            float t  = 1.0f - rr;                                        \
            float u  = w2c * (rr * (2.0f - rr));                         \
            float s  = -2.0f * t * u;                                    \
            float sp = s * aq;                                           \
            su[r] = (_Float16)u; sn[r] = (_Float16)(-sp);                \
            sv[r] = (_Float16)s;                                         \
        }                                                                \
        const int smp2 = (st) * 16 + j;                                  \
        f16x4 pa = {su[0], su[1], su[2], su[3]};                         \
        f16x4 pb = {sn[0], sn[1], sn[2], sn[3]};                         \
        f16x4 pc = {sv[0], sv[1], sv[2], sv[3]};                         \
        *(f16x4*)&usp[smp2 * USTR + h4]       = pa;                      \
        *(f16x4*)&usp[smp2 * USTR + 128 + h4] = pb;                      \
        *(f16x4*)&sst[smp2 * SSTR + h4]       = pc;                      \
    }
    EWST(0)
    EWST(1)
#undef EWST

    __syncthreads();   // barrier 1: u/-sp/s staged by all h-tiles

    // ---- rhs GEMM (waves 0,1): rhs = [A^T|B^T].[u;-sp], K=256; D lands in solve layout ----
    f32x4 racc = {0.0f, 0.0f, 0.0f, 0.0f};
    if (wave < 2) {
#pragma unroll
        for (int kc = 0; kc < 8; ++kc) {
            f16x8 af = *(const f16x8*)&ABT[j * ASTR + (kc << 5) + (grp << 3)];
            f16x8 bf = *(const f16x8*)&usp[(wave * 16 + j) * USTR + (kc << 5) + (grp << 3)];
            racc = __builtin_amdgcn_mfma_f32_16x16x32_f16(af, bf, racc, 0, 0, 0);
        }
    }

    // ---- M = I + B~^T diag(s) B~ via MFMA; afrag = s (*) B via v_pk_mul_f16 ----
    f32x4 acc[4];
    {
        f32x4 ident;
#pragma unroll
        for (int r = 0; r < 4; ++r) ident[r] = ((grp << 2) + r == j) ? 1.0f : 0.0f;
#pragma unroll
        for (int gs = 0; gs < 4; ++gs) acc[gs] = ident;
    }
#pragma unroll
    for (int kc = 0; kc < 4; ++kc) {
        f16x8 bfrag = *(const f16x8*)&ABT[j * ASTR + 128 + (kc << 5) + (grp << 3)];
#pragma unroll
        for (int gs = 0; gs < 4; ++gs) {
            f16x8 sfrag = *(const f16x8*)&sst[(wave * 4 + gs) * SSTR + (kc << 5) + (grp << 3)];
            f16x8 afrag = sfrag * bfrag;   // v_pk_mul_f16 x4
            acc[gs] = __builtin_amdgcn_mfma_f32_16x16x32_f16(afrag, bfrag, acc[gs], 0, 0, 0);
        }
    }

    __syncthreads();   // barrier 2: all reads of Wff/Yff/ABT/usp/sst done -> Mscr overlay

    float* Mscr = (float*)(smem + OFF_MSCR);
#pragma unroll
    for (int gs = 0; gs < 4; ++gs) {
        float4 v;
        v.x = acc[gs][0]; v.y = acc[gs][1]; v.z = acc[gs][2]; v.w = acc[gs][3];
        *(float4*)&Mscr[mswz(wave * 4 + gs, j * 20 + (grp << 2))] = v;
    }

    __syncthreads();   // barrier 3: scratch complete

    // ---- solve (waves 0,1; 16 samples each; 4 lanes/sample, 4 rows/lane) ----
    // Packed-f32 Gauss-Jordan: rows as float2 pairs, v_pk_fma_f32 elimination.
    if (wave >= 2) return;
    const int sl = lane & 15;            // sample within this wave's half
    const int rb = lane >> 4;            // row block (rows 4rb..4rb+3)
    const int s  = wave * 16 + sl;       // sample within block

    v2f M2[4][8];
    float r4[4], d4[4];
#pragma unroll
    for (int r = 0; r < 4; ++r) {
        const int ro = (4 * rb + r) * 20;
        float4 v0 = *(const float4*)&Mscr[mswz(s, ro + 0)];
        float4 v1 = *(const float4*)&Mscr[mswz(s, ro + 4)];
        float4 v2 = *(const float4*)&Mscr[mswz(s, ro + 8)];
        float4 v3 = *(const float4*)&Mscr[mswz(s, ro + 12)];
        M2[r][0] = (v2f){v0.x, v0.y}; M2[r][1] = (v2f){v0.z, v0.w};
        M2[r][2] = (v2f){v1.x, v1.y}; M2[r][3] = (v2f){v1.z, v1.w};
        M2[r][4] = (v2f){v2.x, v2.y}; M2[r][5] = (v2f){v2.z, v2.w};
        M2[r][6] = (v2f){v3.x, v3.y}; M2[r][7] = (v2f){v3.z, v3.w};
        r4[r] = racc[r];
        d4[r] = 1.0f;
    }

#pragma unroll
    for (int k = 0; k < 16; ++k) {
        const int src = sl + ((k >> 2) << 4);
        float piv = __shfl(M2[k & 3][k >> 1][k & 1], src, 64);
        float rk  = __shfl(r4[k & 3], src, 64);
        float invp = __builtin_amdgcn_rcpf(piv);
        invp = invp * (2.0f - piv * invp);
        float f[4];
#pragma unroll
        for (int r = 0; r < 4; ++r) {
            float fr = M2[r][k >> 1][k & 1] * invp;
            const bool isk = ((rb << 2) + r) == k;
            f[r]  = isk ? 0.0f : fr;
            d4[r] = isk ? piv : d4[r];
            r4[r] = fmaf(-f[r], rk, r4[r]);
        }
        const int i2s = (k >> 1) + (k & 1);
#pragma unroll
        for (int i2 = i2s; i2 < 8; ++i2) {
            float p0 = (2 * i2 == k) ? piv : __shfl(M2[k & 3][i2][0], src, 64);
            float p1 = __shfl(M2[k & 3][i2][1], src, 64);
            v2f pv = {p0, p1};
#pragma unroll
            for (int r = 0; r < 4; ++r) {
                v2f fv = {-f[r], -f[r]};
                M2[r][i2] = __builtin_elementwise_fma(fv, pv, M2[r][i2]);
            }
        }
    }

    float4 xo;
    {
        float i0 = __builtin_amdgcn_rcpf(d4[0]); i0 = i0 * (2.0f - d4[0] * i0);
        float i1 = __builtin_amdgcn_rcpf(d4[1]); i1 = i1 * (2.0f - d4[1] * i1);
        float i2 = __builtin_amdgcn_rcpf(d4[2]); i2 = i2 * (2.0f - d4[2] * i2);
        float i3 = __builtin_amdgcn_rcpf(d4[3]); i3 = i3 * (2.0f - d4[3] * i3);
        xo.x = r4[0] * i0; xo.y = r4[1] * i1; xo.z = r4[2] * i2; xo.w = r4[3] * i3;
    }
    *(float4*)&out[(s0 + s) * DIMQ + (rb << 2)] = xo;
}

extern "C" void kernel_launch(void* const* d_in, const int* in_sizes, int n_in,
                              void* d_out, int out_size, void* d_ws, size_t ws_size,
                              hipStream_t stream) {
    const float* y  = (const float*)d_in[0];
    const float* W1 = (const float*)d_in[1];
    const float* b1 = (const float*)d_in[2];
    const float* w2 = (const float*)d_in[3];
    float* out = (float*)d_out;
    const int batch = in_sizes[0] / 32;          // 32768
    const int blocks = (batch + SPB - 1) / SPB;  // 1024
    lag_accel_kernel<<<blocks, NTHREADS, 0, stream>>>(y, W1, b1, w2, out);
}

// Round 16
// 20.776 us; speedup vs baseline: 1.0798x; 1.0798x over previous
//
#include <hip/hip_runtime.h>
#include <math.h>

#define DIMQ 16
#define HID  128
#define SPB  16          // samples per block (4 waves; each wave owns TWO 16-h tiles)
#define NTHREADS 256

typedef __attribute__((ext_vector_type(8))) _Float16 f16x8;  // MFMA A/B frag (4 VGPRs)
typedef __attribute__((ext_vector_type(4))) _Float16 f16x4;  // packed b64 store
typedef __attribute__((ext_vector_type(4))) float f32x4;     // MFMA acc
typedef __attribute__((ext_vector_type(2))) float v2f;       // packed f32 (v_pk_fma_f32)

// f16 strides (elements)
#define ASTR 280         // ABT[16][280]: [A^T | B^T]
#define USTR 280         // usp[16][280]: u at h'=0..127, -sp at h'=128..255
#define SSTR 136         // sst[16][136]: s values

// LDS layout (bytes). Mscr overlays [0,20480) AFTER barrier #2 (all regions dead by then).
#define OFF_WFF  0       // f16 frag-major [8][4][16][8] = 8192
#define OFF_YFF  8192    // f16 frag-major [4][16][8]    = 1024 -> 9216
#define OFF_ABT  9216    // f16[16][280] = 8960 -> 18176
#define OFF_USP  18176   // f16[16][280] = 8960 -> 27136
#define OFF_SST  27136   // f16[16][136] = 4352 -> 31488
#define OFF_MSCR 0       // f32 16*320 = 20480 (overlay)
#define LDS_BYTES 31488  // -> 4+ blocks/CU by LDS; waves are the limiter (4 blocks @ cap-128)

// XOR-swizzle inside each sample's 320-f32 M-scratch (v7-validated).
__device__ __forceinline__ int mswz(int s, int off) {
    return s * 320 + (off ^ ((s & 7) << 2));
}
__device__ __forceinline__ f16x8 pack8(float4 a, float4 b) {
    f16x8 r;
    r[0]=(_Float16)a.x; r[1]=(_Float16)a.y; r[2]=(_Float16)a.z; r[3]=(_Float16)a.w;
    r[4]=(_Float16)b.x; r[5]=(_Float16)b.y; r[6]=(_Float16)b.z; r[7]=(_Float16)b.w;
    return r;
}

// cap-128 register regime (v14-proven, no spills); 4-wave blocks -> 4 resident blocks/CU.
__global__ __launch_bounds__(NTHREADS, 4)
void lag_accel_kernel(const float* __restrict__ y,    // [BATCH][32]
                      const float* __restrict__ W1,   // [128][32]
                      const float* __restrict__ b1,   // [128]
                      const float* __restrict__ w2,   // [128]
                      float* __restrict__ out)        // [BATCH][16]
{
    __shared__ __align__(16) char smem[LDS_BYTES];
    _Float16* Wff = (_Float16*)(smem + OFF_WFF);   // frag-major W1 rows
    _Float16* Yff = (_Float16*)(smem + OFF_YFF);   // frag-major y (one 16-sample tile)
    _Float16* ABT = (_Float16*)(smem + OFF_ABT);   // [16][280]: [j][h]=A[h][j], [j][128+h]=B[h][j]
    _Float16* usp = (_Float16*)(smem + OFF_USP);   // [16][280]: u / -sp
    _Float16* sst = (_Float16*)(smem + OFF_SST);   // [16][136]: s

    const int tid = threadIdx.x;
    const long long s0 = (long long)blockIdx.x * SPB;

    // ---- staging (all vectorized b128/b64 writes) ----
#pragma unroll
    for (int it = 0; it < 2; ++it) {       // Wff: 512 frag slots, 2 per thread
        const int slot = tid + it * 256;   // = ht*64 + grp*16 + j
        const int ht_ = slot >> 6, grp_ = (slot >> 4) & 3, j_ = slot & 15;
        const float4* src = (const float4*)(W1 + (ht_ * 16 + j_) * 32 + (grp_ << 3));
        *(f16x8*)&Wff[slot * 8] = pack8(src[0], src[1]);
    }
    if (tid < 128) {                       // Yff: 16 samples x 32
        const int grp_ = (tid >> 5) & 3, j_ = (tid >> 1) & 15, hf = tid & 1;
        float4 v = *(const float4*)(y + (s0 + j_) * 32 + (grp_ << 3) + (hf << 2));
        f16x4 p; p[0]=(_Float16)v.x; p[1]=(_Float16)v.y; p[2]=(_Float16)v.z; p[3]=(_Float16)v.w;
        *(f16x4*)&Yff[((grp_ * 16 + j_) << 3) + (hf << 2)] = p;
    }
#pragma unroll
    for (int it = 0; it < 2; ++it) {       // ABT: column-wise loads -> contiguous b128 writes
        const int idx = tid + it * 256;
        const int k = idx & 31, h0 = (idx >> 5) << 3;
        float v[8];
#pragma unroll
        for (int i = 0; i < 8; ++i) v[i] = W1[(h0 + i) * 32 + k];
        f16x8 p;
#pragma unroll
        for (int i = 0; i < 8; ++i) p[i] = (_Float16)v[i];
        const int j_ = (k < 16) ? k : (k - 16);
        const int off = (k < 16) ? h0 : (128 + h0);
        *(f16x8*)&ABT[j_ * ASTR + off] = p;
    }

    const int wave = tid >> 6;
    const int lane = tid & 63;
    const int grp  = lane >> 4;      // MFMA quadrant (k-slice / D row-block)
    const int j    = lane & 15;      // MFMA m/n index (= sample index in this tile)

    __syncthreads();   // barrier 0: staging complete

    // ---- z/aqd GEMMs for this wave's TWO h-tiles (ht = 2*wave, 2*wave+1) ----
    f16x8 yf = *(const f16x8*)&Yff[((grp * 16 + j) << 3)];

    f32x4 zacc[2], aacc[2];
    float4 w2v[2];
#pragma unroll
    for (int t = 0; t < 2; ++t) {
        const int ht = wave * 2 + t;
        f16x8 aW  = *(const f16x8*)&Wff[((ht * 4 + grp) * 16 + j) * 8];
        f16x8 aAl = *(const f16x8*)&Wff[((ht * 4 + (grp & 1)) * 16 + j) * 8];
        f16x8 aA;
#pragma unroll
        for (int e = 0; e < 8; ++e) aA[e] = (grp >= 2) ? aAl[e] : (_Float16)0.0f;
        float4 b1v = *(const float4*)&b1[ht * 16 + (grp << 2)];
        w2v[t] = *(const float4*)&w2[ht * 16 + (grp << 2)];
        f32x4 ci; ci[0] = b1v.x; ci[1] = b1v.y; ci[2] = b1v.z; ci[3] = b1v.w;
        f32x4 zf = {0.0f, 0.0f, 0.0f, 0.0f};
        zacc[t] = __builtin_amdgcn_mfma_f32_16x16x32_f16(aW, yf, ci, 0, 0, 0);
        aacc[t] = __builtin_amdgcn_mfma_f32_16x16x32_f16(aA, yf, zf, 0, 0, 0);
    }

    // ---- elementwise per h-tile t: h = 16*(2w+t)+4grp+r, sample = j; stage f16 ----
#define EWST(t)                                                          \
    {                                                                    \
        const int h4 = (wave * 2 + (t)) * 16 + (grp << 2);               \
        _Float16 su[4], sn[4], sv[4];                                    \
        _Pragma("unroll")                                                \
        for (int r = 0; r < 4; ++r) {                                    \
            float z  = zacc[t][r], aq = aacc[t][r];                      \
            float w2c = (r == 0) ? w2v[t].x : (r == 1) ? w2v[t].y         \
                       : (r == 2) ? w2v[t].z : w2v[t].w;                 \
            float e  = __expf(2.0f * z);                                 \
            float rr = 2.0f * __builtin_amdgcn_rcpf(e + 1.0f);           \
            float t_ = 1.0f - rr;                                        \
            float u  = w2c * (rr * (2.0f - rr));                         \
            float s  = -2.0f * t_ * u;                                   \
            float sp = s * aq;                                           \
            su[r] = (_Float16)u; sn[r] = (_Float16)(-sp);                \
            sv[r] = (_Float16)s;                                         \
        }                                                                \
        f16x4 pa = {su[0], su[1], su[2], su[3]};                         \
        f16x4 pb = {sn[0], sn[1], sn[2], sn[3]};                         \
        f16x4 pc = {sv[0], sv[1], sv[2], sv[3]};                         \
        *(f16x4*)&usp[j * USTR + h4]       = pa;                         \
        *(f16x4*)&usp[j * USTR + 128 + h4] = pb;                         \
        *(f16x4*)&sst[j * SSTR + h4]       = pc;                         \
    }
    EWST(0)
    EWST(1)
#undef EWST

    __syncthreads();   // barrier 1: u/-sp/s staged by all h-tiles

    // ---- rhs GEMM (wave 0): rhs = [A^T|B^T].[u;-sp], K=256; D lands in solve layout ----
    f32x4 racc = {0.0f, 0.0f, 0.0f, 0.0f};
    if (wave == 0) {
#pragma unroll
        for (int kc = 0; kc < 8; ++kc) {
            f16x8 af = *(const f16x8*)&ABT[j * ASTR + (kc << 5) + (grp << 3)];
            f16x8 bf = *(const f16x8*)&usp[j * USTR + (kc << 5) + (grp << 3)];
            racc = __builtin_amdgcn_mfma_f32_16x16x32_f16(af, bf, racc, 0, 0, 0);
        }
    }

    // ---- M = I + B~^T diag(s) B~ via MFMA; wave's samples 4w..4w+3 ----
    f32x4 acc[4];
    {
        f32x4 ident;
#pragma unroll
        for (int r = 0; r < 4; ++r) ident[r] = ((grp << 2) + r == j) ? 1.0f : 0.0f;
#pragma unroll
        for (int gs = 0; gs < 4; ++gs) acc[gs] = ident;
    }
#pragma unroll
    for (int kc = 0; kc < 4; ++kc) {
        f16x8 bfrag = *(const f16x8*)&ABT[j * ASTR + 128 + (kc << 5) + (grp << 3)];
#pragma unroll
        for (int gs = 0; gs < 4; ++gs) {
            f16x8 sfrag = *(const f16x8*)&sst[(wave * 4 + gs) * SSTR + (kc << 5) + (grp << 3)];
            f16x8 afrag = sfrag * bfrag;   // v_pk_mul_f16 x4
            acc[gs] = __builtin_amdgcn_mfma_f32_16x16x32_f16(afrag, bfrag, acc[gs], 0, 0, 0);
        }
    }

    __syncthreads();   // barrier 2: all reads of Wff/Yff/ABT/usp/sst done -> Mscr overlay

    float* Mscr = (float*)(smem + OFF_MSCR);
    // M symmetric: D(rows 4grp..4grp+3, col j) == M[j][4grp..4grp+3] -> one b128/sample.
#pragma unroll
    for (int gs = 0; gs < 4; ++gs) {
        float4 v;
        v.x = acc[gs][0]; v.y = acc[gs][1]; v.z = acc[gs][2]; v.w = acc[gs][3];
        *(float4*)&Mscr[mswz(wave * 4 + gs, j * 20 + (grp << 2))] = v;
    }

    __syncthreads();   // barrier 3: scratch complete

    // ---- solve (wave 0; ALL 16 samples; 4 lanes/sample, 4 rows/lane) ----
    if (wave != 0) return;
    const int sl = lane & 15;            // sample
    const int rb = lane >> 4;            // row block (rows 4rb..4rb+3)

    v2f M2[4][8];
    float r4[4], d4[4];
#pragma unroll
    for (int r = 0; r < 4; ++r) {
        const int ro = (4 * rb + r) * 20;
        float4 v0 = *(const float4*)&Mscr[mswz(sl, ro + 0)];
        float4 v1 = *(const float4*)&Mscr[mswz(sl, ro + 4)];
        float4 v2 = *(const float4*)&Mscr[mswz(sl, ro + 8)];
        float4 v3 = *(const float4*)&Mscr[mswz(sl, ro + 12)];
        M2[r][0] = (v2f){v0.x, v0.y}; M2[r][1] = (v2f){v0.z, v0.w};
        M2[r][2] = (v2f){v1.x, v1.y}; M2[r][3] = (v2f){v1.z, v1.w};
        M2[r][4] = (v2f){v2.x, v2.y}; M2[r][5] = (v2f){v2.z, v2.w};
        M2[r][6] = (v2f){v3.x, v3.y}; M2[r][7] = (v2f){v3.z, v3.w};
        r4[r] = racc[r];                 // rhs already in the right lane/reg
        d4[r] = 1.0f;
    }

    // Packed-f32 Gauss-Jordan (v14-validated), non-normalizing, triangular skip.
#pragma unroll
    for (int k = 0; k < 16; ++k) {
        const int src = sl + ((k >> 2) << 4);
        float piv = __shfl(M2[k & 3][k >> 1][k & 1], src, 64);
        float rk  = __shfl(r4[k & 3], src, 64);
        float invp = __builtin_amdgcn_rcpf(piv);
        invp = invp * (2.0f - piv * invp);
        float f[4];
#pragma unroll
        for (int r = 0; r < 4; ++r) {
            float fr = M2[r][k >> 1][k & 1] * invp;
            const bool isk = ((rb << 2) + r) == k;
            f[r]  = isk ? 0.0f : fr;
            d4[r] = isk ? piv : d4[r];
            r4[r] = fmaf(-f[r], rk, r4[r]);
        }
        const int i2s = (k >> 1) + (k & 1);
#pragma unroll
        for (int i2 = i2s; i2 < 8; ++i2) {
            float p0 = (2 * i2 == k) ? piv : __shfl(M2[k & 3][i2][0], src, 64);
            float p1 = __shfl(M2[k & 3][i2][1], src, 64);
            v2f pv = {p0, p1};
#pragma unroll
            for (int r = 0; r < 4; ++r) {
                v2f fv = {-f[r], -f[r]};
                M2[r][i2] = __builtin_elementwise_fma(fv, pv, M2[r][i2]);
            }
        }
    }

    float4 xo;
    {
        float i0 = __builtin_amdgcn_rcpf(d4[0]); i0 = i0 * (2.0f - d4[0] * i0);
        float i1 = __builtin_amdgcn_rcpf(d4[1]); i1 = i1 * (2.0f - d4[1] * i1);
        float i2 = __builtin_amdgcn_rcpf(d4[2]); i2 = i2 * (2.0f - d4[2] * i2);
        float i3 = __builtin_amdgcn_rcpf(d4[3]); i3 = i3 * (2.0f - d4[3] * i3);
        xo.x = r4[0] * i0; xo.y = r4[1] * i1; xo.z = r4[2] * i2; xo.w = r4[3] * i3;
    }
    *(float4*)&out[(s0 + sl) * DIMQ + (rb << 2)] = xo;
}

extern "C" void kernel_launch(void* const* d_in, const int* in_sizes, int n_in,
                              void* d_out, int out_size, void* d_ws, size_t ws_size,
                              hipStream_t stream) {
    const float* y  = (const float*)d_in[0];
    const float* W1 = (const float*)d_in[1];
    const float* b1 = (const float*)d_in[2];
    const float* w2 = (const float*)d_in[3];
    float* out = (float*)d_out;
    const int batch = in_sizes[0] / 32;          // 32768
    const int blocks = (batch + SPB - 1) / SPB;  // 2048
    lag_accel_kernel<<<blocks, NTHREADS, 0, stream>>>(y, W1, b1, w2, out);
}

// Round 17
// 19.571 us; speedup vs baseline: 1.1463x; 1.0616x over previous
//
#include <hip/hip_runtime.h>
#include <math.h>

#define DIMQ 16
#define HID  128
#define SPB  32          // samples per block (4 waves; wave owns TWO h-tiles, BOTH sample-tiles)
#define NTHREADS 256

typedef __attribute__((ext_vector_type(8))) _Float16 f16x8;  // MFMA A/B frag (4 VGPRs)
typedef __attribute__((ext_vector_type(4))) _Float16 f16x4;  // packed b64 store
typedef __attribute__((ext_vector_type(4))) float f32x4;     // MFMA acc
typedef __attribute__((ext_vector_type(2))) float v2f;       // packed f32 (v_pk_fma_f32)

// LDS layout (bytes): power-of-2 rows + XOR bank-skew. Mscr overlays ALL after barrier 2.
#define OFF_WFF  0       // f16 frag-major [8][4][16][8] = 8192
#define OFF_ABT  8192    // f16[16][256] XOR-swz = 8192 -> 16384
#define OFF_USP  16384   // f16[32][256] XOR-swz = 16384 -> 32768
#define OFF_SST  32768   // f16[32][128] XOR-swz = 8192 -> 40960
#define OFF_MSCR 0       // f32 32*320 = 40960 (overlay)
#define LDS_BYTES 40960  // x4 = 160 KiB exactly -> 4 blocks/CU

// XOR bank-skew in 16B (8-f16) granules within a row; bijective, alignment-preserving.
__device__ __forceinline__ int axor(int row, int off) { return off ^ ((row & 7) << 3); }
// XOR-swizzle inside each sample's 320-f32 M-scratch (v7-validated).
__device__ __forceinline__ int mswz(int s, int off) {
    return s * 320 + (off ^ ((s & 7) << 2));
}
__device__ __forceinline__ f16x8 pack8(float4 a, float4 b) {
    f16x8 r;
    r[0]=(_Float16)a.x; r[1]=(_Float16)a.y; r[2]=(_Float16)a.z; r[3]=(_Float16)a.w;
    r[4]=(_Float16)b.x; r[5]=(_Float16)b.y; r[6]=(_Float16)b.z; r[7]=(_Float16)b.w;
    return r;
}

// cap-128 register regime (v14-proven); 4-wave blocks -> 4 resident blocks/CU.
__global__ __launch_bounds__(NTHREADS, 4)
void lag_accel_kernel(const float* __restrict__ y,    // [BATCH][32]
                      const float* __restrict__ W1,   // [128][32]
                      const float* __restrict__ b1,   // [128]
                      const float* __restrict__ w2,   // [128]
                      float* __restrict__ out)        // [BATCH][16]
{
    __shared__ __align__(16) char smem[LDS_BYTES];
    _Float16* Wff = (_Float16*)(smem + OFF_WFF);   // frag-major W1 rows
    _Float16* ABT = (_Float16*)(smem + OFF_ABT);   // [16][256]: [j][h]=A[h][j], [j][128+h]=B[h][j]
    _Float16* usp = (_Float16*)(smem + OFF_USP);   // [32][256]: u / -sp
    _Float16* sst = (_Float16*)(smem + OFF_SST);   // [32][128]: s

    const int tid = threadIdx.x;
    const long long s0 = (long long)blockIdx.x * SPB;

    const int wave = tid >> 6;
    const int lane = tid & 63;
    const int grp  = lane >> 4;      // MFMA quadrant (k-slice / D row-block)
    const int j    = lane & 15;      // MFMA m/n index (= sample index within tile)

    // ---- y directly to registers (v2/v5-proven; no LDS, no barrier dependency) ----
    f16x8 yf[2];
#pragma unroll
    for (int st = 0; st < 2; ++st) {
        const float4* yg = (const float4*)(y + (s0 + st * 16 + j) * 32 + (grp << 3));
        yf[st] = pack8(yg[0], yg[1]);
    }

    // ---- staging (vectorized b128 writes; XOR bank-skew) ----
#pragma unroll
    for (int it = 0; it < 2; ++it) {       // Wff: 512 frag slots, 2 per thread
        const int slot = tid + it * 256;   // = ht*64 + grp*16 + j
        const int ht_ = slot >> 6, grp_ = (slot >> 4) & 3, j_ = slot & 15;
        const float4* src = (const float4*)(W1 + (ht_ * 16 + j_) * 32 + (grp_ << 3));
        *(f16x8*)&Wff[slot * 8] = pack8(src[0], src[1]);
    }
#pragma unroll
    for (int it = 0; it < 2; ++it) {       // ABT: column-wise loads -> contiguous b128 writes
        const int idx = tid + it * 256;
        const int k = idx & 31, h0 = (idx >> 5) << 3;
        float v[8];
#pragma unroll
        for (int i = 0; i < 8; ++i) v[i] = W1[(h0 + i) * 32 + k];
        f16x8 p;
#pragma unroll
        for (int i = 0; i < 8; ++i) p[i] = (_Float16)v[i];
        const int j_ = (k < 16) ? k : (k - 16);
        const int off = (k < 16) ? h0 : (128 + h0);
        *(f16x8*)&ABT[(j_ << 8) + axor(j_, off)] = p;
    }

    __syncthreads();   // barrier 0: Wff/ABT staged

    // ---- z/aqd GEMMs: TWO h-tiles x TWO sample-tiles per wave ----
    f32x4 zacc[2][2], aacc[2][2];
    float4 w2v[2];
#pragma unroll
    for (int t = 0; t < 2; ++t) {
        const int ht = wave * 2 + t;
        f16x8 aW  = *(const f16x8*)&Wff[((ht * 4 + grp) * 16 + j) * 8];
        f16x8 aAl = *(const f16x8*)&Wff[((ht * 4 + (grp & 1)) * 16 + j) * 8];
        f16x8 aA;
#pragma unroll
        for (int e = 0; e < 8; ++e) aA[e] = (grp >= 2) ? aAl[e] : (_Float16)0.0f;
        float4 b1v = *(const float4*)&b1[ht * 16 + (grp << 2)];
        w2v[t] = *(const float4*)&w2[ht * 16 + (grp << 2)];
        f32x4 ci; ci[0] = b1v.x; ci[1] = b1v.y; ci[2] = b1v.z; ci[3] = b1v.w;
        f32x4 zf = {0.0f, 0.0f, 0.0f, 0.0f};
#pragma unroll
        for (int st = 0; st < 2; ++st) {
            zacc[t][st] = __builtin_amdgcn_mfma_f32_16x16x32_f16(aW, yf[st], ci, 0, 0, 0);
            aacc[t][st] = __builtin_amdgcn_mfma_f32_16x16x32_f16(aA, yf[st], zf, 0, 0, 0);
        }
    }

    // ---- elementwise: h = 16*(2w+t)+4grp+r, sample = st*16+j; stage f16 (XOR-swz) ----
#define EWST(t, st)                                                      \
    {                                                                    \
        const int h4 = (wave * 2 + (t)) * 16 + (grp << 2);               \
        const int smp2 = (st) * 16 + j;                                  \
        _Float16 su[4], sn[4], sv[4];                                    \
        _Pragma("unroll")                                                \
        for (int r = 0; r < 4; ++r) {                                    \
            float z  = zacc[t][st][r], aq = aacc[t][st][r];              \
            float w2c = (r == 0) ? w2v[t].x : (r == 1) ? w2v[t].y         \
                       : (r == 2) ? w2v[t].z : w2v[t].w;                 \
            float e  = __expf(2.0f * z);                                 \
            float rr = 2.0f * __builtin_amdgcn_rcpf(e + 1.0f);           \
            float t_ = 1.0f - rr;                                        \
            float u  = w2c * (rr * (2.0f - rr));                         \
            float s  = -2.0f * t_ * u;                                   \
            float sp = s * aq;                                           \
            su[r] = (_Float16)u; sn[r] = (_Float16)(-sp);                \
            sv[r] = (_Float16)s;                                         \
        }                                                                \
        f16x4 pa = {su[0], su[1], su[2], su[3]};                         \
        f16x4 pb = {sn[0], sn[1], sn[2], sn[3]};                         \
        f16x4 pc = {sv[0], sv[1], sv[2], sv[3]};                         \
        *(f16x4*)&usp[(smp2 << 8) + axor(smp2, h4)]       = pa;          \
        *(f16x4*)&usp[(smp2 << 8) + axor(smp2, 128 + h4)] = pb;          \
        *(f16x4*)&sst[(smp2 << 7) + axor(smp2, h4)]       = pc;          \
    }
    EWST(0, 0) EWST(0, 1) EWST(1, 0) EWST(1, 1)
#undef EWST

    __syncthreads();   // barrier 1: u/-sp/s staged by all h-tiles

    // ---- rhs GEMM (waves 0,1): rhs = [A^T|B^T].[u;-sp], K=256; D lands in solve layout ----
    f32x4 racc = {0.0f, 0.0f, 0.0f, 0.0f};
    if (wave < 2) {
#pragma unroll
        for (int kc = 0; kc < 8; ++kc) {
            const int o = (kc << 5) + (grp << 3);
            const int smp = wave * 16 + j;
            f16x8 af = *(const f16x8*)&ABT[(j << 8) + axor(j, o)];
            f16x8 bf = *(const f16x8*)&usp[(smp << 8) + axor(smp, o)];
            racc = __builtin_amdgcn_mfma_f32_16x16x32_f16(af, bf, racc, 0, 0, 0);
        }
    }

    // ---- M = I + B~^T diag(s) B~ via MFMA; wave's samples 8w..8w+7 ----
    f32x4 acc[8];
    {
        f32x4 ident;
#pragma unroll
        for (int r = 0; r < 4; ++r) ident[r] = ((grp << 2) + r == j) ? 1.0f : 0.0f;
#pragma unroll
        for (int gs = 0; gs < 8; ++gs) acc[gs] = ident;
    }
#pragma unroll
    for (int kc = 0; kc < 4; ++kc) {
        const int o = (kc << 5) + (grp << 3);
        f16x8 bfrag = *(const f16x8*)&ABT[(j << 8) + axor(j, 128 + o)];
#pragma unroll
        for (int gs = 0; gs < 8; ++gs) {
            const int smp = wave * 8 + gs;
            f16x8 sfrag = *(const f16x8*)&sst[(smp << 7) + axor(smp, o)];
            f16x8 afrag = sfrag * bfrag;   // v_pk_mul_f16 x4
            acc[gs] = __builtin_amdgcn_mfma_f32_16x16x32_f16(afrag, bfrag, acc[gs], 0, 0, 0);
        }
    }

    __syncthreads();   // barrier 2: all reads of Wff/ABT/usp/sst done -> Mscr overlay

    float* Mscr = (float*)(smem + OFF_MSCR);
    // M symmetric: D(rows 4grp..4grp+3, col j) == M[j][4grp..4grp+3] -> one b128/sample.
#pragma unroll
    for (int gs = 0; gs < 8; ++gs) {
        float4 v;
        v.x = acc[gs][0]; v.y = acc[gs][1]; v.z = acc[gs][2]; v.w = acc[gs][3];
        *(float4*)&Mscr[mswz(wave * 8 + gs, j * 20 + (grp << 2))] = v;
    }

    __syncthreads();   // barrier 3: scratch complete

    // ---- solve (waves 0,1; 16 samples each; 4 lanes/sample, 4 rows/lane) ----
    if (wave >= 2) return;
    const int sl = lane & 15;            // sample within this wave's half
    const int rb = lane >> 4;            // row block (rows 4rb..4rb+3)
    const int s  = wave * 16 + sl;       // sample within block

    v2f M2[4][8];
    float r4[4], d4[4];
#pragma unroll
    for (int r = 0; r < 4; ++r) {
        const int ro = (4 * rb + r) * 20;
        float4 v0 = *(const float4*)&Mscr[mswz(s, ro + 0)];
        float4 v1 = *(const float4*)&Mscr[mswz(s, ro + 4)];
        float4 v2 = *(const float4*)&Mscr[mswz(s, ro + 8)];
        float4 v3 = *(const float4*)&Mscr[mswz(s, ro + 12)];
        M2[r][0] = (v2f){v0.x, v0.y}; M2[r][1] = (v2f){v0.z, v0.w};
        M2[r][2] = (v2f){v1.x, v1.y}; M2[r][3] = (v2f){v1.z, v1.w};
        M2[r][4] = (v2f){v2.x, v2.y}; M2[r][5] = (v2f){v2.z, v2.w};
        M2[r][6] = (v2f){v3.x, v3.y}; M2[r][7] = (v2f){v3.z, v3.w};
        r4[r] = racc[r];                 // rhs already in the right lane/reg
        d4[r] = 1.0f;
    }

    // Packed-f32 Gauss-Jordan (v14-validated), non-normalizing, triangular skip.
#pragma unroll
    for (int k = 0; k < 16; ++k) {
        const int src = sl + ((k >> 2) << 4);
        float piv = __shfl(M2[k & 3][k >> 1][k & 1], src, 64);
        float rk  = __shfl(r4[k & 3], src, 64);
        float invp = __builtin_amdgcn_rcpf(piv);
        invp = invp * (2.0f - piv * invp);
        float f[4];
#pragma unroll
        for (int r = 0; r < 4; ++r) {
            float fr = M2[r][k >> 1][k & 1] * invp;
            const bool isk = ((rb << 2) + r) == k;
            f[r]  = isk ? 0.0f : fr;
            d4[r] = isk ? piv : d4[r];
            r4[r] = fmaf(-f[r], rk, r4[r]);
        }
        const int i2s = (k >> 1) + (k & 1);
#pragma unroll
        for (int i2 = i2s; i2 < 8; ++i2) {
            float p0 = (2 * i2 == k) ? piv : __shfl(M2[k & 3][i2][0], src, 64);
            float p1 = __shfl(M2[k & 3][i2][1], src, 64);
            v2f pv = {p0, p1};
#pragma unroll
            for (int r = 0; r < 4; ++r) {
                v2f fv = {-f[r], -f[r]};
                M2[r][i2] = __builtin_elementwise_fma(fv, pv, M2[r][i2]);
            }
        }
    }

    float4 xo;
    {
        float i0 = __builtin_amdgcn_rcpf(d4[0]); i0 = i0 * (2.0f - d4[0] * i0);
        float i1 = __builtin_amdgcn_rcpf(d4[1]); i1 = i1 * (2.0f - d4[1] * i1);
        float i2 = __builtin_amdgcn_rcpf(d4[2]); i2 = i2 * (2.0f - d4[2] * i2);
        float i3 = __builtin_amdgcn_rcpf(d4[3]); i3 = i3 * (2.0f - d4[3] * i3);
        xo.x = r4[0] * i0; xo.y = r4[1] * i1; xo.z = r4[2] * i2; xo.w = r4[3] * i3;
    }
    *(float4*)&out[(s0 + s) * DIMQ + (rb << 2)] = xo;
}

extern "C" void kernel_launch(void* const* d_in, const int* in_sizes, int n_in,
                              void* d_out, int out_size, void* d_ws, size_t ws_size,
                              hipStream_t stream) {
    const float* y  = (const float*)d_in[0];
    const float* W1 = (const float*)d_in[1];
    const float* b1 = (const float*)d_in[2];
    const float* w2 = (const float*)d_in[3];
    float* out = (float*)d_out;
    const int batch = in_sizes[0] / 32;          // 32768
    const int blocks = (batch + SPB - 1) / SPB;  // 1024
    lag_accel_kernel<<<blocks, NTHREADS, 0, stream>>>(y, W1, b1, w2, out);
}

// Round 18
// 18.890 us; speedup vs baseline: 1.1876x; 1.0360x over previous
//
#include <hip/hip_runtime.h>
#include <math.h>

#define DIMQ 16
#define HID  128
#define SPB  64          // samples per block (8 waves; wave owns ONE h-tile, FOUR sample-tiles)
#define NTHREADS 512

typedef __attribute__((ext_vector_type(8))) _Float16 f16x8;  // MFMA A/B frag (4 VGPRs)
typedef __attribute__((ext_vector_type(4))) _Float16 f16x4;  // packed b64 store
typedef __attribute__((ext_vector_type(4))) float f32x4;     // MFMA acc
typedef __attribute__((ext_vector_type(2))) float v2f;       // packed f32 (v_pk_fma_f32)

// LDS layout (bytes): power-of-2 rows + XOR bank-skew (v17-validated). Mscr overlays ALL.
#define OFF_WFF  0       // f16 frag-major [8][4][16][8] = 8192
#define OFF_ABT  8192    // f16[16][256] XOR-swz = 8192 -> 16384
#define OFF_USP  16384   // f16[64][256] XOR-swz = 32768 -> 49152
#define OFF_SST  49152   // f16[64][128] XOR-swz = 16384 -> 65536
#define OFF_MSCR 0       // f32 64*320 = 81920 (overlay after barrier 2)
#define LDS_BYTES 81920  // x2 = 160 KiB exactly -> 2 blocks/CU, 16 waves/CU

// XOR bank-skew in 16B (8-f16) granules within a row; bijective, alignment-preserving.
__device__ __forceinline__ int axor(int row, int off) { return off ^ ((row & 7) << 3); }
// XOR-swizzle inside each sample's 320-f32 M-scratch (v7-validated).
__device__ __forceinline__ int mswz(int s, int off) {
    return s * 320 + (off ^ ((s & 7) << 2));
}
__device__ __forceinline__ f16x8 pack8(float4 a, float4 b) {
    f16x8 r;
    r[0]=(_Float16)a.x; r[1]=(_Float16)a.y; r[2]=(_Float16)a.z; r[3]=(_Float16)a.w;
    r[4]=(_Float16)b.x; r[5]=(_Float16)b.y; r[6]=(_Float16)b.z; r[7]=(_Float16)b.w;
    return r;
}

// cap-128 register regime (v14-proven): 4 waves/SIMD, 2 resident 8-wave blocks/CU.
__global__ __launch_bounds__(NTHREADS, 4)
void lag_accel_kernel(const float* __restrict__ y,    // [BATCH][32]
                      const float* __restrict__ W1,   // [128][32]
                      const float* __restrict__ b1,   // [128]
                      const float* __restrict__ w2,   // [128]
                      float* __restrict__ out)        // [BATCH][16]
{
    __shared__ __align__(16) char smem[LDS_BYTES];
    _Float16* Wff = (_Float16*)(smem + OFF_WFF);   // frag-major W1 rows
    _Float16* ABT = (_Float16*)(smem + OFF_ABT);   // [16][256]: [j][h]=A[h][j], [j][128+h]=B[h][j]
    _Float16* usp = (_Float16*)(smem + OFF_USP);   // [64][256]: u / -sp
    _Float16* sst = (_Float16*)(smem + OFF_SST);   // [64][128]: s

    const int tid = threadIdx.x;
    const long long s0 = (long long)blockIdx.x * SPB;

    const int wave = tid >> 6;
    const int lane = tid & 63;
    const int grp  = lane >> 4;      // MFMA quadrant (k-slice / D row-block)
    const int j    = lane & 15;      // MFMA m/n index (= sample index within tile)
    const int ht   = wave;           // this wave's h-tile

    // ---- y directly to registers: four 16-sample tiles (coalesced per wave) ----
    f16x8 yf[4];
#pragma unroll
    for (int st = 0; st < 4; ++st) {
        const float4* yg = (const float4*)(y + (s0 + st * 16 + j) * 32 + (grp << 3));
        yf[st] = pack8(yg[0], yg[1]);
    }

    // ---- staging (one b128 write per thread per array) ----
    {
        // Wff: 512 frag slots, slot = tid = ht*64 + grp*16 + j
        const int ht_ = tid >> 6, grp_ = (tid >> 4) & 3, j_ = tid & 15;
        const float4* src = (const float4*)(W1 + (ht_ * 16 + j_) * 32 + (grp_ << 3));
        *(f16x8*)&Wff[tid * 8] = pack8(src[0], src[1]);
    }
    {
        // ABT: column-wise loads -> contiguous b128 writes; tid = hb*32 + k
        const int k = tid & 31, h0 = (tid >> 5) << 3;
        float v[8];
#pragma unroll
        for (int i = 0; i < 8; ++i) v[i] = W1[(h0 + i) * 32 + k];
        f16x8 p;
#pragma unroll
        for (int i = 0; i < 8; ++i) p[i] = (_Float16)v[i];
        const int j_ = (k < 16) ? k : (k - 16);
        const int off = (k < 16) ? h0 : (128 + h0);
        *(f16x8*)&ABT[(j_ << 8) + axor(j_, off)] = p;
    }

    __syncthreads();   // barrier 0: Wff/ABT staged

    // ---- z/aqd GEMMs + elementwise, per sample-tile (sequential -> low reg peak) ----
    f16x8 aW  = *(const f16x8*)&Wff[((ht * 4 + grp) * 16 + j) * 8];
    f16x8 aAl = *(const f16x8*)&Wff[((ht * 4 + (grp & 1)) * 16 + j) * 8];
    f16x8 aA;
#pragma unroll
    for (int e = 0; e < 8; ++e) aA[e] = (grp >= 2) ? aAl[e] : (_Float16)0.0f;
    float4 b1v = *(const float4*)&b1[ht * 16 + (grp << 2)];
    float4 w2v = *(const float4*)&w2[ht * 16 + (grp << 2)];
    f32x4 ci; ci[0] = b1v.x; ci[1] = b1v.y; ci[2] = b1v.z; ci[3] = b1v.w;
    const f32x4 zf = {0.0f, 0.0f, 0.0f, 0.0f};
    const int h4 = ht * 16 + (grp << 2);

#pragma unroll
    for (int st = 0; st < 4; ++st) {
        f32x4 zacc = __builtin_amdgcn_mfma_f32_16x16x32_f16(aW, yf[st], ci, 0, 0, 0);
        f32x4 aacc = __builtin_amdgcn_mfma_f32_16x16x32_f16(aA, yf[st], zf, 0, 0, 0);
        const int smp2 = st * 16 + j;
        _Float16 su[4], sn[4], sv[4];
#pragma unroll
        for (int r = 0; r < 4; ++r) {
            float z  = zacc[r], aq = aacc[r];
            float w2c = (r == 0) ? w2v.x : (r == 1) ? w2v.y
                       : (r == 2) ? w2v.z : w2v.w;
            float e  = __expf(2.0f * z);
            float rr = 2.0f * __builtin_amdgcn_rcpf(e + 1.0f);
            float t_ = 1.0f - rr;
            float u  = w2c * (rr * (2.0f - rr));
            float s  = -2.0f * t_ * u;
            float sp = s * aq;
            su[r] = (_Float16)u; sn[r] = (_Float16)(-sp);
            sv[r] = (_Float16)s;
        }
        f16x4 pa = {su[0], su[1], su[2], su[3]};
        f16x4 pb = {sn[0], sn[1], sn[2], sn[3]};
        f16x4 pc = {sv[0], sv[1], sv[2], sv[3]};
        *(f16x4*)&usp[(smp2 << 8) + axor(smp2, h4)]       = pa;
        *(f16x4*)&usp[(smp2 << 8) + axor(smp2, 128 + h4)] = pb;
        *(f16x4*)&sst[(smp2 << 7) + axor(smp2, h4)]       = pc;
    }

    __syncthreads();   // barrier 1: u/-sp/s staged by all h-tiles

    // ---- rhs GEMM (waves 0-3): rhs = [A^T|B^T].[u;-sp], K=256; D lands in solve layout ----
    f32x4 racc = {0.0f, 0.0f, 0.0f, 0.0f};
    if (wave < 4) {
        const int smp = wave * 16 + j;
#pragma unroll
        for (int kc = 0; kc < 8; ++kc) {
            const int o = (kc << 5) + (grp << 3);
            f16x8 af = *(const f16x8*)&ABT[(j << 8) + axor(j, o)];
            f16x8 bf = *(const f16x8*)&usp[(smp << 8) + axor(smp, o)];
            racc = __builtin_amdgcn_mfma_f32_16x16x32_f16(af, bf, racc, 0, 0, 0);
        }
    }

    // ---- M = I + B~^T diag(s) B~ via MFMA; wave's samples 8w..8w+7 ----
    f32x4 acc[8];
    {
        f32x4 ident;
#pragma unroll
        for (int r = 0; r < 4; ++r) ident[r] = ((grp << 2) + r == j) ? 1.0f : 0.0f;
#pragma unroll
        for (int gs = 0; gs < 8; ++gs) acc[gs] = ident;
    }
#pragma unroll
    for (int kc = 0; kc < 4; ++kc) {
        const int o = (kc << 5) + (grp << 3);
        f16x8 bfrag = *(const f16x8*)&ABT[(j << 8) + axor(j, 128 + o)];
#pragma unroll
        for (int gs = 0; gs < 8; ++gs) {
            const int smp = wave * 8 + gs;
            f16x8 sfrag = *(const f16x8*)&sst[(smp << 7) + axor(smp, o)];
            f16x8 afrag = sfrag * bfrag;   // v_pk_mul_f16 x4
            acc[gs] = __builtin_amdgcn_mfma_f32_16x16x32_f16(afrag, bfrag, acc[gs], 0, 0, 0);
        }
    }

    __syncthreads();   // barrier 2: all reads of Wff/ABT/usp/sst done -> Mscr overlay

    float* Mscr = (float*)(smem + OFF_MSCR);
    // M symmetric: D(rows 4grp..4grp+3, col j) == M[j][4grp..4grp+3] -> one b128/sample.
#pragma unroll
    for (int gs = 0; gs < 8; ++gs) {
        float4 v;
        v.x = acc[gs][0]; v.y = acc[gs][1]; v.z = acc[gs][2]; v.w = acc[gs][3];
        *(float4*)&Mscr[mswz(wave * 8 + gs, j * 20 + (grp << 2))] = v;
    }

    __syncthreads();   // barrier 3: scratch complete

    // ---- solve (waves 0-3; 16 samples each; 4 lanes/sample, 4 rows/lane) ----
    if (wave >= 4) return;
    const int sl = lane & 15;            // sample within this wave's quarter
    const int rb = lane >> 4;            // row block (rows 4rb..4rb+3)
    const int s  = wave * 16 + sl;       // sample within block

    v2f M2[4][8];
    float r4[4], d4[4];
#pragma unroll
    for (int r = 0; r < 4; ++r) {
        const int ro = (4 * rb + r) * 20;
        float4 v0 = *(const float4*)&Mscr[mswz(s, ro + 0)];
        float4 v1 = *(const float4*)&Mscr[mswz(s, ro + 4)];
        float4 v2 = *(const float4*)&Mscr[mswz(s, ro + 8)];
        float4 v3 = *(const float4*)&Mscr[mswz(s, ro + 12)];
        M2[r][0] = (v2f){v0.x, v0.y}; M2[r][1] = (v2f){v0.z, v0.w};
        M2[r][2] = (v2f){v1.x, v1.y}; M2[r][3] = (v2f){v1.z, v1.w};
        M2[r][4] = (v2f){v2.x, v2.y}; M2[r][5] = (v2f){v2.z, v2.w};
        M2[r][6] = (v2f){v3.x, v3.y}; M2[r][7] = (v2f){v3.z, v3.w};
        r4[r] = racc[r];                 // rhs already in the right lane/reg
        d4[r] = 1.0f;
    }

    // Packed-f32 Gauss-Jordan (v14-validated), non-normalizing, triangular skip.
#pragma unroll
    for (int k = 0; k < 16; ++k) {
        const int src = sl + ((k >> 2) << 4);
        float piv = __shfl(M2[k & 3][k >> 1][k & 1], src, 64);
        float rk  = __shfl(r4[k & 3], src, 64);
        float invp = __builtin_amdgcn_rcpf(piv);
        invp = invp * (2.0f - piv * invp);
        float f[4];
#pragma unroll
        for (int r = 0; r < 4; ++r) {
            float fr = M2[r][k >> 1][k & 1] * invp;
            const bool isk = ((rb << 2) + r) == k;
            f[r]  = isk ? 0.0f : fr;
            d4[r] = isk ? piv : d4[r];
            r4[r] = fmaf(-f[r], rk, r4[r]);
        }
        const int i2s = (k >> 1) + (k & 1);
#pragma unroll
        for (int i2 = i2s; i2 < 8; ++i2) {
            float p0 = (2 * i2 == k) ? piv : __shfl(M2[k & 3][i2][0], src, 64);
            float p1 = __shfl(M2[k & 3][i2][1], src, 64);
            v2f pv = {p0, p1};
#pragma unroll
            for (int r = 0; r < 4; ++r) {
                v2f fv = {-f[r], -f[r]};
                M2[r][i2] = __builtin_elementwise_fma(fv, pv, M2[r][i2]);
            }
        }
    }

    float4 xo;
    {
        float i0 = __builtin_amdgcn_rcpf(d4[0]); i0 = i0 * (2.0f - d4[0] * i0);
        float i1 = __builtin_amdgcn_rcpf(d4[1]); i1 = i1 * (2.0f - d4[1] * i1);
        float i2 = __builtin_amdgcn_rcpf(d4[2]); i2 = i2 * (2.0f - d4[2] * i2);
        float i3 = __builtin_amdgcn_rcpf(d4[3]); i3 = i3 * (2.0f - d4[3] * i3);
        xo.x = r4[0] * i0; xo.y = r4[1] * i1; xo.z = r4[2] * i2; xo.w = r4[3] * i3;
    }
    *(float4*)&out[(s0 + s) * DIMQ + (rb << 2)] = xo;
}

extern "C" void kernel_launch(void* const* d_in, const int* in_sizes, int n_in,
                              void* d_out, int out_size, void* d_ws, size_t ws_size,
                              hipStream_t stream) {
    const float* y  = (const float*)d_in[0];
    const float* W1 = (const float*)d_in[1];
    const float* b1 = (const float*)d_in[2];
    const float* w2 = (const float*)d_in[3];
    float* out = (float*)d_out;
    const int batch = in_sizes[0] / 32;          // 32768
    const int blocks = (batch + SPB - 1) / SPB;  // 512
    lag_accel_kernel<<<blocks, NTHREADS, 0, stream>>>(y, W1, b1, w2, out);
}